// Round 4
// baseline (156.765 us; speedup 1.0000x reference)
//
#include <hip/hip_runtime.h>
#include <hip/hip_cooperative_groups.h>
#include <stdint.h>

namespace cg = cooperative_groups;

// Problem constants: x shape [T*B, C, H, W] = [256, 128, 32, 32]
static constexpr int   T_     = 8;
static constexpr int   C_     = 128;
static constexpr int   N_     = 32 * 128 * 32 * 32;  // 4194304 sites
static constexpr int   CHUNK_ = N_ / 4;              // 1048576 sites per chunk
static constexpr int   NBLKC_ = 1024;                // cooperative grid (4 blocks/CU)
static constexpr int   NBLK_  = N_ / 4 / 256;        // 4096 (fallback grid)
static constexpr float LR_    = 0.1f;

typedef float v4f __attribute__((ext_vector_type(4)));

// ---------------------------------------------------------------------------
// Fused cooperative kernel: phase1 recurrence (spikes in regs) -> part[b]
// -> grid.sync -> redundant scalar -> phase2 out-write from regs.
// Block b, chunk k covers plane (b + 1024k); channel = b & 127 for all k.
// ---------------------------------------------------------------------------
__global__ __launch_bounds__(256, 4) void k_fused(const float* __restrict__ x,
                                                  const float* __restrict__ thresh,
                                                  float* __restrict__ part,
                                                  float* __restrict__ out) {
    const float thre = thresh[0];
    const int tid = threadIdx.x;
    const int b   = blockIdx.x;

    unsigned pbp[4];        // packed spike bits, 16 sites (static-indexed!)
    float local = 0.0f;     // new_thre partial

#pragma unroll
    for (int k = 0; k < 4; ++k) {
        const size_t base = (size_t)k * CHUNK_ + (size_t)b * 1024 + tid * 4;
        float    mem[4];
        unsigned pb[4] = {0, 0, 0, 0};
#pragma unroll
        for (int i = 0; i < 4; ++i) mem[i] = 0.5f * thre;
#pragma unroll
        for (int t = 0; t < T_; ++t) {
            const v4f xv = __builtin_nontemporal_load(
                reinterpret_cast<const v4f*>(x + (size_t)t * N_ + base));
#pragma unroll
            for (int i = 0; i < 4; ++i) {
                mem[i] += xv[i];
                if (mem[i] - thre >= 0.0f) {   // heaviside(mem - cur)
                    mem[i] -= thre;            // mem - s*cur
                    pb[i] |= (1u << t);
                }
            }
        }
        pbp[k] = pb[0] | (pb[1] << 8) | (pb[2] << 16) | (pb[3] << 24);
#pragma unroll
        for (int i = 0; i < 4; ++i) {
            const int   cnt = __popc(pb[i]);
            const float compen_mem = mem[i] - 0.5f * thre;
            const float cv = fminf(compen_mem + (float)cnt * thre, (float)T_ * thre);
            if (cv > 0.0f && cnt > 0) local += cv / (float)cnt;
        }
    }

    // block reduce -> part[b] (written unconditionally, no zeroing needed)
#pragma unroll
    for (int off = 32; off > 0; off >>= 1) local += __shfl_down(local, off, 64);
    __shared__ float sm[8];   // [0..3] wave partials; [4..7] channel-reduce partials
    const int lane = tid & 63;
    const int wid  = tid >> 6;
    if (lane == 0) sm[wid] = local;
    __syncthreads();
    if (tid == 0) part[b] = sm[0] + sm[1] + sm[2] + sm[3];

    cg::this_grid().sync();

    // redundant per-block scalar: channel c partial = sum of part[g*128 + c]
    float v = 0.0f;
    if (tid < C_) {
        float sum = 0.0f;
#pragma unroll
        for (int g = 0; g < NBLKC_ / C_; ++g) sum += part[g * C_ + tid];
        const float ub = sum * (1.0f / 32768.0f);  // mean over B*H*W
        v = (thre > ub) ? (ub - thre) : 0.0f;      // diff * mask
    }
#pragma unroll
    for (int off = 32; off > 0; off >>= 1) v += __shfl_down(v, off, 64);
    __syncthreads();
    if (lane == 0) sm[4 + wid] = v;   // waves 2,3 contribute 0
    __syncthreads();
    const float s = thre + LR_ * 2.0f * (sm[4] + sm[5] + sm[6] + sm[7]) * (1.0f / (float)C_);

    // phase 2: out[t, site] = spike_bit ? s : 0, straight from registers
#pragma unroll
    for (int k = 0; k < 4; ++k) {
        const size_t base = (size_t)k * CHUNK_ + (size_t)b * 1024 + tid * 4;
        const unsigned pk = pbp[k];
#pragma unroll
        for (int t = 0; t < T_; ++t) {
            v4f o;
            o.x = ((pk >> t) & 1)        ? s : 0.0f;
            o.y = ((pk >> (8 + t)) & 1)  ? s : 0.0f;
            o.z = ((pk >> (16 + t)) & 1) ? s : 0.0f;
            o.w = ((pk >> (24 + t)) & 1) ? s : 0.0f;
            __builtin_nontemporal_store(o, reinterpret_cast<v4f*>(out + (size_t)t * N_ + base));
        }
    }
}

// ===========================================================================
// Fallback 2-kernel path (used only if cooperative launch is unavailable)
// ===========================================================================
template <bool PACK>
__global__ __launch_bounds__(256) void k_fwd(const float* __restrict__ x,
                                             const float* __restrict__ thresh,
                                             uint8_t* __restrict__ spk,
                                             float* __restrict__ part) {
    const float thre = thresh[0];
    const int e4   = blockIdx.x * 256 + threadIdx.x;
    const int base = e4 * 4;
    float    mem[4];
    unsigned pb[4] = {0, 0, 0, 0};
#pragma unroll
    for (int i = 0; i < 4; ++i) mem[i] = 0.5f * thre;
#pragma unroll
    for (int t = 0; t < T_; ++t) {
        const v4f xv = __builtin_nontemporal_load(
            reinterpret_cast<const v4f*>(x + (size_t)t * N_ + base));
#pragma unroll
        for (int i = 0; i < 4; ++i) {
            mem[i] += xv[i];
            if (mem[i] - thre >= 0.0f) { mem[i] -= thre; pb[i] |= (1u << t); }
        }
    }
    if (PACK) {
        reinterpret_cast<unsigned*>(spk)[e4] =
            pb[0] | (pb[1] << 8) | (pb[2] << 16) | (pb[3] << 24);
    }
    float local = 0.0f;
#pragma unroll
    for (int i = 0; i < 4; ++i) {
        const int   cnt = __popc(pb[i]);
        const float compen_mem = mem[i] - 0.5f * thre;
        const float cv = fminf(compen_mem + (float)cnt * thre, (float)T_ * thre);
        if (cv > 0.0f && cnt > 0) local += cv / (float)cnt;
    }
#pragma unroll
    for (int off = 32; off > 0; off >>= 1) local += __shfl_down(local, off, 64);
    __shared__ float wpart[4];
    const int lane = threadIdx.x & 63;
    const int wid  = threadIdx.x >> 6;
    if (lane == 0) wpart[wid] = local;
    __syncthreads();
    if (threadIdx.x == 0) part[blockIdx.x] = wpart[0] + wpart[1] + wpart[2] + wpart[3];
}

__device__ __forceinline__ float compute_scalar4k(const float* __restrict__ part,
                                                  const float thre, float* s_red) {
    float v = 0.0f;
    if (threadIdx.x < C_) {
        float sum = 0.0f;
#pragma unroll
        for (int g = 0; g < NBLK_ / C_; ++g) sum += part[g * C_ + threadIdx.x];
        const float ub = sum * (1.0f / 32768.0f);
        v = (thre > ub) ? (ub - thre) : 0.0f;
    }
#pragma unroll
    for (int off = 32; off > 0; off >>= 1) v += __shfl_down(v, off, 64);
    if ((threadIdx.x & 63) == 0) s_red[1 + (threadIdx.x >> 6)] = v;
    __syncthreads();
    if (threadIdx.x == 0) {
        s_red[0] = thre + LR_ * 2.0f *
                   (s_red[1] + s_red[2] + s_red[3] + s_red[4]) * (1.0f / (float)C_);
    }
    __syncthreads();
    return s_red[0];
}

__global__ __launch_bounds__(256) void k_out(const uint8_t* __restrict__ spk,
                                             const float* __restrict__ part,
                                             const float* __restrict__ thresh,
                                             float* __restrict__ out) {
    __shared__ float s_red[5];
    const float s = compute_scalar4k(part, thresh[0], s_red);
    const int e4   = blockIdx.x * 256 + threadIdx.x;
    const int base = e4 * 4;
    const unsigned packed = reinterpret_cast<const unsigned*>(spk)[e4];
#pragma unroll
    for (int t = 0; t < T_; ++t) {
        v4f o;
        o.x = ((packed >> t) & 1)        ? s : 0.0f;
        o.y = ((packed >> (8 + t)) & 1)  ? s : 0.0f;
        o.z = ((packed >> (16 + t)) & 1) ? s : 0.0f;
        o.w = ((packed >> (24 + t)) & 1) ? s : 0.0f;
        __builtin_nontemporal_store(o, reinterpret_cast<v4f*>(out + (size_t)t * N_ + base));
    }
}

__global__ __launch_bounds__(256) void k_out_recompute(const float* __restrict__ x,
                                                       const float* __restrict__ part,
                                                       const float* __restrict__ thresh,
                                                       float* __restrict__ out) {
    __shared__ float s_red[5];
    const float thre = thresh[0];
    const float s = compute_scalar4k(part, thre, s_red);
    const int e4   = blockIdx.x * 256 + threadIdx.x;
    const int base = e4 * 4;
    float mem[4];
#pragma unroll
    for (int i = 0; i < 4; ++i) mem[i] = 0.5f * thre;
#pragma unroll
    for (int t = 0; t < T_; ++t) {
        const v4f xv = __builtin_nontemporal_load(
            reinterpret_cast<const v4f*>(x + (size_t)t * N_ + base));
        v4f o;
#pragma unroll
        for (int i = 0; i < 4; ++i) {
            mem[i] += xv[i];
            if (mem[i] - thre >= 0.0f) { mem[i] -= thre; o[i] = s; }
            else                        { o[i] = 0.0f; }
        }
        __builtin_nontemporal_store(o, reinterpret_cast<v4f*>(out + (size_t)t * N_ + base));
    }
}

extern "C" void kernel_launch(void* const* d_in, const int* in_sizes, int n_in,
                              void* d_out, int out_size, void* d_ws, size_t ws_size,
                              hipStream_t stream) {
    const float* x      = (const float*)d_in[0];
    const float* thresh = (const float*)d_in[1];
    float*       out    = (float*)d_out;

    // ws layout: [0, 16K) part (1024 used by fused / 4096 by fallback)
    //            [16K, 16K + N_) packed spikes (fallback only)
    float*   part = (float*)d_ws;
    uint8_t* spk  = (uint8_t*)d_ws + NBLK_ * sizeof(float);

    void* args[] = {(void*)&x, (void*)&thresh, (void*)&part, (void*)&out};
    hipError_t e = hipLaunchCooperativeKernel((const void*)k_fused, dim3(NBLKC_),
                                              dim3(256), args, 0, stream);
    if (e == hipSuccess) return;
    (void)hipGetLastError();  // clear sticky error, use fallback path

    const bool pack = ws_size >= (size_t)(NBLK_ * sizeof(float) + N_);
    if (pack) {
        k_fwd<true><<<NBLK_, 256, 0, stream>>>(x, thresh, spk, part);
        k_out<<<NBLK_, 256, 0, stream>>>(spk, part, thresh, out);
    } else {
        k_fwd<false><<<NBLK_, 256, 0, stream>>>(x, thresh, nullptr, part);
        k_out_recompute<<<NBLK_, 256, 0, stream>>>(x, part, thresh, out);
    }
}

// Round 5
// 54.891 us; speedup vs baseline: 2.8559x; 2.8559x over previous
//
#include <hip/hip_runtime.h>
#include <stdint.h>

// Problem constants: x shape [T*B, C, H, W] = [256, 128, 32, 32]
static constexpr int   T_    = 8;
static constexpr int   C_    = 128;
static constexpr int   N_    = 32 * 128 * 32 * 32;  // B*C*H*W = 4194304 sites
static constexpr int   N4_   = N_ / 4;              // 1048576 float4/uchar4 per t
static constexpr int   NBLK_ = N_ / 4 / 256;        // 4096 blocks for K1
static constexpr float LR_   = 0.1f;

typedef float v4f __attribute__((ext_vector_type(4)));

// ---------------------------------------------------------------------------
// K1: IF recurrence over T, pack spike bits, per-block new_thre partial.
// 4 consecutive sites/thread (float4). Block = one (b,c) plane of 1024 sites,
// channel = blockIdx & 127. part[blockIdx] written unconditionally.
// x loads are TEMPORAL (keep x LLC-resident across graph replays);
// spk/out writes are NT (don't evict x from LLC).
// ---------------------------------------------------------------------------
template <bool PACK>
__global__ __launch_bounds__(256) void k_fwd(const float* __restrict__ x,
                                             const float* __restrict__ thresh,
                                             uint8_t* __restrict__ spk,
                                             float* __restrict__ part) {
    const float thre = thresh[0];
    const int e4   = blockIdx.x * 256 + threadIdx.x;
    const int base = e4 * 4;
    float    mem[4];
    unsigned pb[4] = {0, 0, 0, 0};
#pragma unroll
    for (int i = 0; i < 4; ++i) mem[i] = 0.5f * thre;
#pragma unroll
    for (int t = 0; t < T_; ++t) {
        const v4f xv = *reinterpret_cast<const v4f*>(x + (size_t)t * N_ + base);
#pragma unroll
        for (int i = 0; i < 4; ++i) {
            mem[i] += xv[i];
            if (mem[i] - thre >= 0.0f) {   // heaviside(mem - cur)
                mem[i] -= thre;            // mem - s*cur
                pb[i] |= (1u << t);
            }
        }
    }
    if (PACK) {
        __builtin_nontemporal_store(
            pb[0] | (pb[1] << 8) | (pb[2] << 16) | (pb[3] << 24),
            reinterpret_cast<unsigned*>(spk) + e4);
    }
    float local = 0.0f;
#pragma unroll
    for (int i = 0; i < 4; ++i) {
        const int   cnt = __popc(pb[i]);
        const float compen_mem = mem[i] - 0.5f * thre;
        const float cv = fminf(compen_mem + (float)cnt * thre, (float)T_ * thre);
        if (cv > 0.0f && cnt > 0) local += cv / (float)cnt;
    }
#pragma unroll
    for (int off = 32; off > 0; off >>= 1) local += __shfl_down(local, off, 64);
    __shared__ float wpart[4];
    const int lane = threadIdx.x & 63;
    const int wid  = threadIdx.x >> 6;
    if (lane == 0) wpart[wid] = local;
    __syncthreads();
    if (threadIdx.x == 0) part[blockIdx.x] = wpart[0] + wpart[1] + wpart[2] + wpart[3];
}

// ---------------------------------------------------------------------------
// K2: single-block scalar: ub[c] = sum_g part[g*128+c] / 32768;
//     scal = thre + 0.2 * mean_c((ub-thre) * (thre > ub))
// ---------------------------------------------------------------------------
__global__ __launch_bounds__(128) void k_scalar(const float* __restrict__ part,
                                                const float* __restrict__ thresh,
                                                float* __restrict__ scal) {
    const float thre = thresh[0];
    float sum = 0.0f;
#pragma unroll
    for (int g = 0; g < NBLK_ / C_; ++g) sum += part[g * C_ + threadIdx.x];
    const float ub = sum * (1.0f / 32768.0f);       // mean over B*H*W
    float v = (thre > ub) ? (ub - thre) : 0.0f;     // diff * mask
#pragma unroll
    for (int off = 32; off > 0; off >>= 1) v += __shfl_down(v, off, 64);
    __shared__ float partial[2];
    if ((threadIdx.x & 63) == 0) partial[threadIdx.x >> 6] = v;
    __syncthreads();
    if (threadIdx.x == 0) {
        scal[0] = thre + LR_ * 2.0f * (partial[0] + partial[1]) * (1.0f / (float)C_);
    }
}

// ---------------------------------------------------------------------------
// K3: fill-clone output writer. Grid covers out linearly in float4 units;
// each block owns 4096 consecutive float4 (64 KB), so t = blockIdx>>8 is
// block-uniform and stores are perfectly contiguous per wave iteration.
// spk bytes for the block's 4096 sites (16 KB) are L2/LLC-resident re-reads.
// ---------------------------------------------------------------------------
__global__ __launch_bounds__(256) void k_out_fill(const uint8_t* __restrict__ spk,
                                                  const float* __restrict__ scal,
                                                  float* __restrict__ out) {
    const float s = scal[0];
    const int t = blockIdx.x >> 8;                  // 256 blocks per timestep
    const int site4_base = (blockIdx.x & 255) * 4096;
    const unsigned* sp32 = reinterpret_cast<const unsigned*>(spk);
#pragma unroll
    for (int it = 0; it < 16; ++it) {
        const int i4 = it * 256 + threadIdx.x;      // 0..4095 within block
        const unsigned p = sp32[site4_base + i4];   // 4 sites' spike bytes
        v4f o;
        o.x = ((p >> t) & 1)        ? s : 0.0f;
        o.y = ((p >> (8 + t)) & 1)  ? s : 0.0f;
        o.z = ((p >> (16 + t)) & 1) ? s : 0.0f;
        o.w = ((p >> (24 + t)) & 1) ? s : 0.0f;
        __builtin_nontemporal_store(
            o, reinterpret_cast<v4f*>(out) + (size_t)t * N4_ + site4_base + i4);
    }
}

// ---------------------------------------------------------------------------
// Fallback (ws too small for spike pack): recompute recurrence from x
// ---------------------------------------------------------------------------
__global__ __launch_bounds__(256) void k_out_recompute(const float* __restrict__ x,
                                                       const float* __restrict__ thresh,
                                                       const float* __restrict__ scal,
                                                       float* __restrict__ out) {
    const float thre = thresh[0];
    const float s    = scal[0];
    const int e4   = blockIdx.x * 256 + threadIdx.x;
    const int base = e4 * 4;
    float mem[4];
#pragma unroll
    for (int i = 0; i < 4; ++i) mem[i] = 0.5f * thre;
#pragma unroll
    for (int t = 0; t < T_; ++t) {
        const v4f xv = *reinterpret_cast<const v4f*>(x + (size_t)t * N_ + base);
        v4f o;
#pragma unroll
        for (int i = 0; i < 4; ++i) {
            mem[i] += xv[i];
            if (mem[i] - thre >= 0.0f) { mem[i] -= thre; o[i] = s; }
            else                        { o[i] = 0.0f; }
        }
        __builtin_nontemporal_store(o, reinterpret_cast<v4f*>(out + (size_t)t * N_ + base));
    }
}

extern "C" void kernel_launch(void* const* d_in, const int* in_sizes, int n_in,
                              void* d_out, int out_size, void* d_ws, size_t ws_size,
                              hipStream_t stream) {
    const float* x      = (const float*)d_in[0];
    const float* thresh = (const float*)d_in[1];
    float*       out    = (float*)d_out;

    // ws layout: [0,16K) part[4096] | [16K,16K+4) scal | [32K, 32K+N_) spikes
    float*   part = (float*)d_ws;
    float*   scal = (float*)((uint8_t*)d_ws + 16384);
    uint8_t* spk  = (uint8_t*)d_ws + 32768;
    const bool pack = ws_size >= (size_t)(32768 + N_);

    if (pack) {
        k_fwd<true><<<NBLK_, 256, 0, stream>>>(x, thresh, spk, part);
        k_scalar<<<1, 128, 0, stream>>>(part, thresh, scal);
        k_out_fill<<<T_ * 256, 256, 0, stream>>>(spk, scal, out);
    } else {
        k_fwd<false><<<NBLK_, 256, 0, stream>>>(x, thresh, nullptr, part);
        k_scalar<<<1, 128, 0, stream>>>(part, thresh, scal);
        k_out_recompute<<<NBLK_, 256, 0, stream>>>(x, thresh, scal, out);
    }
}

// Round 6
// 53.012 us; speedup vs baseline: 2.9572x; 1.0354x over previous
//
#include <hip/hip_runtime.h>
#include <stdint.h>

// Problem constants: x shape [T*B, C, H, W] = [256, 128, 32, 32]
static constexpr int   T_    = 8;
static constexpr int   C_    = 128;
static constexpr int   N_    = 32 * 128 * 32 * 32;  // B*C*H*W = 4194304 sites
static constexpr int   N4_   = N_ / 4;              // float4 units per timestep
static constexpr int   NPLANE_ = N_ / 1024;         // 4096 (b,c) planes
static constexpr int   NBLK1_  = N_ / 8 / 256;      // 2048 blocks for K1 (8 sites/thr)
static constexpr int   NBLKF_  = N_ / 4 / 256;      // 4096 blocks (fallback path)
static constexpr float LR_   = 0.1f;

typedef float v4f __attribute__((ext_vector_type(4)));

// ---------------------------------------------------------------------------
// K1: IF recurrence over T, 8 sites/thread (2x float4 per t -> 16 loads in
// flight). Block = 2048 consecutive sites = planes {2b, 2b+1}; waves 0-1 own
// plane 2b, waves 2-3 own plane 2b+1. part[plane] = plane's new_thre partial
// (plane p has channel p & 127). x loads temporal; spk stores NT.
// ---------------------------------------------------------------------------
template <bool PACK>
__global__ __launch_bounds__(256) void k_fwd(const float* __restrict__ x,
                                             const float* __restrict__ thresh,
                                             uint8_t* __restrict__ spk,
                                             float* __restrict__ part) {
    const float thre = thresh[0];
    const int tid  = threadIdx.x;
    const int base = (blockIdx.x * 256 + tid) * 8;

    float    mem[8];
    unsigned pb[8] = {0, 0, 0, 0, 0, 0, 0, 0};
#pragma unroll
    for (int i = 0; i < 8; ++i) mem[i] = 0.5f * thre;

#pragma unroll
    for (int t = 0; t < T_; ++t) {
        const v4f xa = *reinterpret_cast<const v4f*>(x + (size_t)t * N_ + base);
        const v4f xb = *reinterpret_cast<const v4f*>(x + (size_t)t * N_ + base + 4);
#pragma unroll
        for (int i = 0; i < 4; ++i) {
            mem[i] += xa[i];
            if (mem[i] - thre >= 0.0f) { mem[i] -= thre; pb[i] |= (1u << t); }
        }
#pragma unroll
        for (int i = 0; i < 4; ++i) {
            mem[4 + i] += xb[i];
            if (mem[4 + i] - thre >= 0.0f) { mem[4 + i] -= thre; pb[4 + i] |= (1u << t); }
        }
    }

    if (PACK) {
        typedef unsigned v2u __attribute__((ext_vector_type(2)));
        v2u pk;
        pk.x = pb[0] | (pb[1] << 8) | (pb[2] << 16) | (pb[3] << 24);
        pk.y = pb[4] | (pb[5] << 8) | (pb[6] << 16) | (pb[7] << 24);
        __builtin_nontemporal_store(pk, reinterpret_cast<v2u*>(spk) + blockIdx.x * 256 + tid);
    }

    float local = 0.0f;
#pragma unroll
    for (int i = 0; i < 8; ++i) {
        const int   cnt = __popc(pb[i]);
        const float compen_mem = mem[i] - 0.5f * thre;
        const float cv = fminf(compen_mem + (float)cnt * thre, (float)T_ * thre);
        if (cv > 0.0f && cnt > 0) local += cv / (float)cnt;
    }

    // per-wave reduce; waves 0-1 -> plane 2b, waves 2-3 -> plane 2b+1
#pragma unroll
    for (int off = 32; off > 0; off >>= 1) local += __shfl_down(local, off, 64);
    __shared__ float wpart[4];
    const int lane = tid & 63;
    const int wid  = tid >> 6;
    if (lane == 0) wpart[wid] = local;
    __syncthreads();
    if (tid == 0) {
        part[2 * blockIdx.x]     = wpart[0] + wpart[1];
        part[2 * blockIdx.x + 1] = wpart[2] + wpart[3];
    }
}

// ---------------------------------------------------------------------------
// Redundant scalar: each block reduces part[4096] (L2-resident, 16 KB).
// ub[c] = sum_g part[g*128+c] / 32768; s = thre + 0.2*mean_c((ub-thre)*(thre>ub))
// ---------------------------------------------------------------------------
__device__ __forceinline__ float compute_scalar(const float* __restrict__ part,
                                                const float thre, float* s_red) {
    float v = 0.0f;
    if (threadIdx.x < C_) {
        float sum = 0.0f;
#pragma unroll
        for (int g = 0; g < NPLANE_ / C_; ++g) sum += part[g * C_ + threadIdx.x];
        const float ub = sum * (1.0f / 32768.0f);   // mean over B*H*W
        v = (thre > ub) ? (ub - thre) : 0.0f;       // diff * mask
    }
#pragma unroll
    for (int off = 32; off > 0; off >>= 1) v += __shfl_down(v, off, 64);
    if ((threadIdx.x & 63) == 0) s_red[1 + (threadIdx.x >> 6)] = v;
    __syncthreads();
    if (threadIdx.x == 0) {
        s_red[0] = thre + LR_ * 2.0f *
                   (s_red[1] + s_red[2] + s_red[3] + s_red[4]) * (1.0f / (float)C_);
    }
    __syncthreads();
    return s_red[0];
}

// ---------------------------------------------------------------------------
// K2: fill-clone writer. Block owns 4096 consecutive float4 of out (64 KB),
// t = blockIdx>>8 block-uniform, stores perfectly contiguous. spk re-reads
// (16 KB/block) are L2/LLC-hot from K1.
// ---------------------------------------------------------------------------
__global__ __launch_bounds__(256) void k_out_fill(const uint8_t* __restrict__ spk,
                                                  const float* __restrict__ part,
                                                  const float* __restrict__ thresh,
                                                  float* __restrict__ out) {
    __shared__ float s_red[5];
    const float s = compute_scalar(part, thresh[0], s_red);

    const int t = blockIdx.x >> 8;                  // 256 blocks per timestep
    const int site4_base = (blockIdx.x & 255) * 4096;
    const unsigned* sp32 = reinterpret_cast<const unsigned*>(spk);
#pragma unroll
    for (int it = 0; it < 16; ++it) {
        const int i4 = it * 256 + threadIdx.x;      // 0..4095 within block
        const unsigned p = sp32[site4_base + i4];   // 4 sites' spike bytes
        v4f o;
        o.x = ((p >> t) & 1)        ? s : 0.0f;
        o.y = ((p >> (8 + t)) & 1)  ? s : 0.0f;
        o.z = ((p >> (16 + t)) & 1) ? s : 0.0f;
        o.w = ((p >> (24 + t)) & 1) ? s : 0.0f;
        __builtin_nontemporal_store(
            o, reinterpret_cast<v4f*>(out) + (size_t)t * N4_ + site4_base + i4);
    }
}

// ---------------------------------------------------------------------------
// Fallback (ws too small for spike pack): recompute recurrence from x
// ---------------------------------------------------------------------------
__global__ __launch_bounds__(256) void k_out_recompute(const float* __restrict__ x,
                                                       const float* __restrict__ part,
                                                       const float* __restrict__ thresh,
                                                       float* __restrict__ out) {
    __shared__ float s_red[5];
    const float thre = thresh[0];
    const float s = compute_scalar(part, thre, s_red);
    const int base = (blockIdx.x * 256 + threadIdx.x) * 8;
    float mem[8];
#pragma unroll
    for (int i = 0; i < 8; ++i) mem[i] = 0.5f * thre;
#pragma unroll
    for (int t = 0; t < T_; ++t) {
        const v4f xa = *reinterpret_cast<const v4f*>(x + (size_t)t * N_ + base);
        const v4f xb = *reinterpret_cast<const v4f*>(x + (size_t)t * N_ + base + 4);
        v4f oa, ob;
#pragma unroll
        for (int i = 0; i < 4; ++i) {
            mem[i] += xa[i];
            if (mem[i] - thre >= 0.0f) { mem[i] -= thre; oa[i] = s; } else oa[i] = 0.0f;
        }
#pragma unroll
        for (int i = 0; i < 4; ++i) {
            mem[4 + i] += xb[i];
            if (mem[4 + i] - thre >= 0.0f) { mem[4 + i] -= thre; ob[i] = s; } else ob[i] = 0.0f;
        }
        __builtin_nontemporal_store(oa, reinterpret_cast<v4f*>(out + (size_t)t * N_ + base));
        __builtin_nontemporal_store(ob, reinterpret_cast<v4f*>(out + (size_t)t * N_ + base + 4));
    }
}

extern "C" void kernel_launch(void* const* d_in, const int* in_sizes, int n_in,
                              void* d_out, int out_size, void* d_ws, size_t ws_size,
                              hipStream_t stream) {
    const float* x      = (const float*)d_in[0];
    const float* thresh = (const float*)d_in[1];
    float*       out    = (float*)d_out;

    // ws layout: [0,16K) part[4096] | [32K, 32K+N_) packed spike bytes
    float*   part = (float*)d_ws;
    uint8_t* spk  = (uint8_t*)d_ws + 32768;
    const bool pack = ws_size >= (size_t)(32768 + N_);

    if (pack) {
        k_fwd<true><<<NBLK1_, 256, 0, stream>>>(x, thresh, spk, part);
        k_out_fill<<<T_ * 256, 256, 0, stream>>>(spk, part, thresh, out);
    } else {
        k_fwd<false><<<NBLK1_, 256, 0, stream>>>(x, thresh, nullptr, part);
        k_out_recompute<<<NBLK1_, 256, 0, stream>>>(x, part, thresh, out);
    }
}